// Round 11
// baseline (63.916 us; speedup 1.0000x reference)
//
#include <hip/hip_runtime.h>

// EfficientRelativePositionalEncoding, MI355X (gfx950)
// B=2, N=2048, H=8, HID=16.  out[b][h][i][j], fp32, 268 MB write-bound.
//
// R11 = R8 structure (47.1us) + two final probes:
//  (a) PERSISTENT BLOCKS: grid 1024 (4 blocks/CU resident, all co-resident),
//      each block processes 4 rows (row = rep*1024 + blk). The fold prologue
//      runs ONCE per block instead of 4x, and stores flow continuously across
//      rows (no inter-block ramp/drain seams). voff/vx0/fragments are
//      rep-invariant; only xb/xi/yi/zi and pb recompute per rep.
//  (b) NONTEMPORAL STORES: output is write-only; nt skips L2 allocation ->
//      no 268MB of L2 fill/evict churn in a 32MB L2.
//
// Prologue (block-parallel, one barrier): weight fold into LDS tables:
//   sA1[32r][16k]: rows 0..7 = Afold[k][h]=sum_m Wd2[k][m]*Wf[m][h], 8+ = 0
//   sA2[32r][16k]: same with Wr2 x Wf[8:16]
//   sW[6][16]:     f16 feature weights k-ordered: Wd1,bd1,Wr1r0,r1,r2,br1
//   sC[8]:         c[h] = bf + bd2@Wf[0:8] + br2@Wf[8:16]  (f32)
//
// Main loop: per 32-pair tile, D = Wc^T . F via two chained
// mfma_f32_32x32x16_f16 (K-half 1: dist feats, K-half 2: dir feats).
// A and B frags share the (lane-group, elem)->k convention so any HW
// k-permutation cancels. C/D (HW-verified): col=lane&31, regs 0..3 ->
// h = reg + 4*(lane>>5). Feature layer in PACKED f16; output bias in
// loop-invariant MFMA C-in. Uniform-SGPR base + u32 voffsets; 16-tile loop
// fully unrolled (t2*128B folds into store immediates). Direct stores: per
// reg, two fully-written 128B segments per instruction. No inter-wave deps.

#define BB 2
#define NN 2048
#define HH 8
#define GRID 1024
#define REPS 4

typedef _Float16 f16x2  __attribute__((ext_vector_type(2)));
typedef _Float16 f16x8  __attribute__((ext_vector_type(8)));
typedef float    f32x16 __attribute__((ext_vector_type(16)));

union W8 { f16x8 v; f16x2 p[4]; };

static __device__ __forceinline__ f16x2 pkrtz(float a, float b) {
    return __builtin_bit_cast(f16x2, __builtin_amdgcn_cvt_pkrtz(a, b));
}

// grid = 1024 blocks, 256 threads = 4 waves; wave w owns j in [512w, 512w+512)
__global__ __launch_bounds__(256, 4) void erpe_main(
    const float* __restrict__ xyz,
    const float* __restrict__ Wd1, const float* __restrict__ bd1,
    const float* __restrict__ Wd2, const float* __restrict__ bd2,
    const float* __restrict__ Wr1, const float* __restrict__ br1,
    const float* __restrict__ Wr2, const float* __restrict__ br2,
    const float* __restrict__ Wf,  const float* __restrict__ bf,
    float* __restrict__ out)
{
    __shared__ _Float16 sA1[32 * 16];   // [row h(pad 32)][k 16]
    __shared__ _Float16 sA2[32 * 16];
    __shared__ _Float16 sW[6 * 16];     // wd, bd, w0, w1, w2, br (k-ordered)
    __shared__ float    sC[8];

    const int t = threadIdx.x;

    // ---- block-parallel fold prologue (ONCE per block) ----
    for (int idx = t; idx < 384; idx += 256) {   // zero rows 8..31
        sA1[128 + idx] = (_Float16)0.f;
        sA2[128 + idx] = (_Float16)0.f;
    }
    if (t < 128) {                               // k = t>>3, h = t&7
        const int k = t >> 3, h = t & 7;
        float sa = 0.f, sb = 0.f;
        #pragma unroll
        for (int m = 0; m < 8; ++m) {
            sa = fmaf(Wd2[k * 8 + m], Wf[m * 8 + h], sa);
            sb = fmaf(Wr2[k * 8 + m], Wf[(m + 8) * 8 + h], sb);
        }
        sA1[h * 16 + k] = (_Float16)sa;
        sA2[h * 16 + k] = (_Float16)sb;
    }
    if (t < 16) {                                // feature weights, f16
        sW[t]      = (_Float16)Wd1[t];
        sW[16 + t] = (_Float16)bd1[t];
        sW[32 + t] = (_Float16)Wr1[t];
        sW[48 + t] = (_Float16)Wr1[16 + t];
        sW[64 + t] = (_Float16)Wr1[32 + t];
        sW[80 + t] = (_Float16)br1[t];
    }
    if (t < 8) {                                 // c[h]
        float s = bf[t];
        #pragma unroll
        for (int m = 0; m < 8; ++m)
            s = fmaf(bd2[m], Wf[m * 8 + t],
                fmaf(br2[m], Wf[(m + 8) * 8 + t], s));
        sC[t] = s;
    }
    __syncthreads();

    const int wave = t >> 6;
    const int lane = t & 63;
    const int g    = lane >> 5;        // k-half group within frag
    const int jl   = lane & 31;        // pair-column within tile / h-row for A
    const int kb   = g * 8;

    // ---- MFMA-ready A fragments + packed weights from LDS ----
    const f16x8 A1 = *(const f16x8*)(sA1 + jl * 16 + kb);
    const f16x8 A2 = *(const f16x8*)(sA2 + jl * 16 + kb);
    const W8 wd = { *(const f16x8*)(sW + kb) };
    const W8 bd = { *(const f16x8*)(sW + 16 + kb) };
    const W8 w0 = { *(const f16x8*)(sW + 32 + kb) };
    const W8 w1 = { *(const f16x8*)(sW + 48 + kb) };
    const W8 w2 = { *(const f16x8*)(sW + 64 + kb) };
    const W8 br = { *(const f16x8*)(sW + 80 + kb) };

    // ---- output bias folded into loop-invariant MFMA C-in ----
    f32x16 accInit;
    #pragma unroll
    for (int q = 0; q < 16; ++q) accInit[q] = 0.f;
    #pragma unroll
    for (int r = 0; r < 4; ++r) accInit[r] = sC[g * 4 + r];

    // ---- rep-invariant per-lane u32 voffsets ----
    const unsigned v0 = (unsigned)(4 * g) * (NN * NN) + wave * 512 + jl;
    unsigned voff[4];
    #pragma unroll
    for (int r = 0; r < 4; ++r) voff[r] = v0 + (unsigned)r * (NN * NN);
    const unsigned vx0 = (unsigned)(wave * 512 + jl) * 3;

    const f16x2 z2 = { (_Float16)0.f, (_Float16)0.f };

    for (int rep = 0; rep < REPS; ++rep) {
        const int row = rep * GRID + blockIdx.x;   // band-contiguous mapping
        const int i   = row & (NN - 1);
        const int b   = row >> 11;

        const float* xb = xyz + (size_t)b * NN * 3;             // uniform
        const float xi = xb[i * 3 + 0];
        const float yi = xb[i * 3 + 1];
        const float zi = xb[i * 3 + 2];

        float* pb = out + ((size_t)b * HH) * (size_t)NN * NN + (size_t)i * NN;

        #pragma unroll
        for (int t2 = 0; t2 < 16; ++t2) {      // 16 tiles of 32 j per wave
            const unsigned vx = vx0 + t2 * 96;
            const float ax = xb[vx + 0];
            const float ay = xb[vx + 1];
            const float az = xb[vx + 2];
            const float dx = ax - xi, dy = ay - yi, dz = az - zi;
            const float r2 = fmaf(dx, dx, fmaf(dy, dy, dz * dz));
            const float d  = __builtin_amdgcn_sqrtf(r2);
            const float inv = __builtin_amdgcn_rcpf(d + 1e-7f);
            const float ux = dx * inv, uy = dy * inv, uz = dz * inv;

            const f16x2 d2  = pkrtz(d, d);
            const f16x2 ux2 = pkrtz(ux, ux);
            const f16x2 uy2 = pkrtz(uy, uy);
            const f16x2 uz2 = pkrtz(uz, uz);

            W8 Btd, Btr;
            #pragma unroll
            for (int p = 0; p < 4; ++p) {
                f16x2 td = d2 * wd.p[p] + bd.p[p];
                f16x2 tr = ux2 * w0.p[p] + (uy2 * w1.p[p] + (uz2 * w2.p[p] + br.p[p]));
                Btd.p[p] = __builtin_elementwise_max(td, z2);
                Btr.p[p] = __builtin_elementwise_max(tr, z2);
            }

            f32x16 acc;
            acc = __builtin_amdgcn_mfma_f32_32x32x16_f16(A1, Btd.v, accInit, 0, 0, 0);
            acc = __builtin_amdgcn_mfma_f32_32x32x16_f16(A2, Btr.v, acc,     0, 0, 0);

            // nt store: reg r -> plane h = r + 4*g, col j; t2*32 folds to imm
            #pragma unroll
            for (int r = 0; r < 4; ++r)
                __builtin_nontemporal_store(acc[r], &pb[voff[r] + t2 * 32]);
        }
    }
}

extern "C" void kernel_launch(void* const* d_in, const int* in_sizes, int n_in,
                              void* d_out, int out_size, void* d_ws, size_t ws_size,
                              hipStream_t stream) {
    const float* xyz = (const float*)d_in[0];
    const float* Wd1 = (const float*)d_in[1];
    const float* bd1 = (const float*)d_in[2];
    const float* Wd2 = (const float*)d_in[3];
    const float* bd2 = (const float*)d_in[4];
    const float* Wr1 = (const float*)d_in[5];
    const float* br1 = (const float*)d_in[6];
    const float* Wr2 = (const float*)d_in[7];
    const float* br2 = (const float*)d_in[8];
    const float* Wf  = (const float*)d_in[9];
    const float* bf  = (const float*)d_in[10];
    float* out = (float*)d_out;

    erpe_main<<<GRID, 256, 0, stream>>>(xyz, Wd1, bd1, Wd2, bd2,
                                        Wr1, br1, Wr2, br2, Wf, bf, out);
}

// Round 12
// 46.891 us; speedup vs baseline: 1.3631x; 1.3631x over previous
//
#include <hip/hip_runtime.h>

// EfficientRelativePositionalEncoding, MI355X (gfx950)
// B=2, N=2048, H=8, HID=16.  out[b][h][i][j], fp32, 268 MB write-bound.
//
// FINAL = R8 structure (best measured: 47.12us R8, 47.13us R10).
// Probed and rejected: R9 xyz->LDS staging (null), R10 XCD swizzle (null),
// R11 persistent blocks + nontemporal stores (-36%: nt bypasses L2's
// write-aggregation in front of the DRAM controllers).
// 268MB / 47.1us = 5.70 TB/s = 81% of the measured pure-fill store ceiling
// (7.0 TB/s, amortized over 150us); remainder is launch/ramp/tail drain.
//
// SINGLE kernel. Prologue (block-parallel, one barrier): weight fold in LDS:
//   sA1[32r][16k]: rows 0..7 = Afold[k][h]=sum_m Wd2[k][m]*Wf[m][h], 8+ = 0
//   sA2[32r][16k]: same with Wr2 x Wf[8:16]
//   sW[6][16]:     f16 feature weights k-ordered: Wd1,bd1,Wr1r0,r1,r2,br1
//   sC[8]:         c[h] = bf + bd2@Wf[0:8] + br2@Wf[8:16]  (f32)
//
// Main loop: per 32-pair tile, D = Wc^T . F via two chained
// mfma_f32_32x32x16_f16 (K-half 1: dist feats, K-half 2: dir feats).
// A and B frags share the (lane-group, elem)->k convention so any HW
// k-permutation cancels. C/D (HW-verified): col=lane&31, regs 0..3 ->
// h = reg + 4*(lane>>5). Feature layer in PACKED f16; output bias in
// loop-invariant MFMA C-in. Uniform-SGPR base + u32 voffsets; 16-tile loop
// fully unrolled (t2*128B folds into store immediates). Direct stores: per
// reg, two fully-written 128B segments per instruction. No inter-wave deps.

#define BB 2
#define NN 2048
#define HH 8

typedef _Float16 f16x2  __attribute__((ext_vector_type(2)));
typedef _Float16 f16x8  __attribute__((ext_vector_type(8)));
typedef float    f32x16 __attribute__((ext_vector_type(16)));

union W8 { f16x8 v; f16x2 p[4]; };

static __device__ __forceinline__ f16x2 pkrtz(float a, float b) {
    return __builtin_bit_cast(f16x2, __builtin_amdgcn_cvt_pkrtz(a, b));
}

// grid = B*N blocks (4096), 256 threads = 4 waves; wave w owns j in [512w, 512w+512)
__global__ __launch_bounds__(256, 4) void erpe_main(
    const float* __restrict__ xyz,
    const float* __restrict__ Wd1, const float* __restrict__ bd1,
    const float* __restrict__ Wd2, const float* __restrict__ bd2,
    const float* __restrict__ Wr1, const float* __restrict__ br1,
    const float* __restrict__ Wr2, const float* __restrict__ br2,
    const float* __restrict__ Wf,  const float* __restrict__ bf,
    float* __restrict__ out)
{
    __shared__ _Float16 sA1[32 * 16];   // [row h(pad 32)][k 16]
    __shared__ _Float16 sA2[32 * 16];
    __shared__ _Float16 sW[6 * 16];     // wd, bd, w0, w1, w2, br (k-ordered)
    __shared__ float    sC[8];

    const int t = threadIdx.x;

    // ---- block-parallel fold prologue ----
    for (int idx = t; idx < 384; idx += 256) {   // zero rows 8..31
        sA1[128 + idx] = (_Float16)0.f;
        sA2[128 + idx] = (_Float16)0.f;
    }
    if (t < 128) {                               // k = t>>3, h = t&7
        const int k = t >> 3, h = t & 7;
        float sa = 0.f, sb = 0.f;
        #pragma unroll
        for (int m = 0; m < 8; ++m) {
            sa = fmaf(Wd2[k * 8 + m], Wf[m * 8 + h], sa);
            sb = fmaf(Wr2[k * 8 + m], Wf[(m + 8) * 8 + h], sb);
        }
        sA1[h * 16 + k] = (_Float16)sa;
        sA2[h * 16 + k] = (_Float16)sb;
    }
    if (t < 16) {                                // feature weights, f16
        sW[t]      = (_Float16)Wd1[t];
        sW[16 + t] = (_Float16)bd1[t];
        sW[32 + t] = (_Float16)Wr1[t];
        sW[48 + t] = (_Float16)Wr1[16 + t];
        sW[64 + t] = (_Float16)Wr1[32 + t];
        sW[80 + t] = (_Float16)br1[t];
    }
    if (t < 8) {                                 // c[h]
        float s = bf[t];
        #pragma unroll
        for (int m = 0; m < 8; ++m)
            s = fmaf(bd2[m], Wf[m * 8 + t],
                fmaf(br2[m], Wf[(m + 8) * 8 + t], s));
        sC[t] = s;
    }
    __syncthreads();

    const int wave = t >> 6;
    const int lane = t & 63;
    const int g    = lane >> 5;        // k-half group within frag
    const int jl   = lane & 31;        // pair-column within tile / h-row for A
    const int kb   = g * 8;

    const int blk = blockIdx.x;
    const int i   = blk & (NN - 1);
    const int b   = blk >> 11;

    // ---- MFMA-ready A fragments + packed weights from LDS ----
    const f16x8 A1 = *(const f16x8*)(sA1 + jl * 16 + kb);
    const f16x8 A2 = *(const f16x8*)(sA2 + jl * 16 + kb);
    const W8 wd = { *(const f16x8*)(sW + kb) };
    const W8 bd = { *(const f16x8*)(sW + 16 + kb) };
    const W8 w0 = { *(const f16x8*)(sW + 32 + kb) };
    const W8 w1 = { *(const f16x8*)(sW + 48 + kb) };
    const W8 w2 = { *(const f16x8*)(sW + 64 + kb) };
    const W8 br = { *(const f16x8*)(sW + 80 + kb) };

    // ---- output bias folded into loop-invariant MFMA C-in ----
    f32x16 accInit;
    #pragma unroll
    for (int q = 0; q < 16; ++q) accInit[q] = 0.f;
    #pragma unroll
    for (int r = 0; r < 4; ++r) accInit[r] = sC[g * 4 + r];

    // ---- uniform SGPR bases + per-lane u32 voffsets ----
    const float* xb = xyz + (size_t)b * NN * 3;                 // uniform
    const float xi = xb[i * 3 + 0];
    const float yi = xb[i * 3 + 1];
    const float zi = xb[i * 3 + 2];

    float* pb = out + ((size_t)b * HH) * (size_t)NN * NN + (size_t)i * NN; // uniform
    const unsigned v0 = (unsigned)(4 * g) * (NN * NN) + wave * 512 + jl;
    unsigned voff[4];
    #pragma unroll
    for (int r = 0; r < 4; ++r) voff[r] = v0 + (unsigned)r * (NN * NN);

    const unsigned vx0 = (unsigned)(wave * 512 + jl) * 3;

    const f16x2 z2 = { (_Float16)0.f, (_Float16)0.f };

    #pragma unroll
    for (int t2 = 0; t2 < 16; ++t2) {      // 16 tiles of 32 j per wave
        const unsigned vx = vx0 + t2 * 96;
        const float ax = xb[vx + 0];
        const float ay = xb[vx + 1];
        const float az = xb[vx + 2];
        const float dx = ax - xi, dy = ay - yi, dz = az - zi;
        const float r2 = fmaf(dx, dx, fmaf(dy, dy, dz * dz));
        const float d  = __builtin_amdgcn_sqrtf(r2);
        const float inv = __builtin_amdgcn_rcpf(d + 1e-7f);
        const float ux = dx * inv, uy = dy * inv, uz = dz * inv;

        const f16x2 d2  = pkrtz(d, d);
        const f16x2 ux2 = pkrtz(ux, ux);
        const f16x2 uy2 = pkrtz(uy, uy);
        const f16x2 uz2 = pkrtz(uz, uz);

        W8 Btd, Btr;
        #pragma unroll
        for (int p = 0; p < 4; ++p) {
            f16x2 td = d2 * wd.p[p] + bd.p[p];
            f16x2 tr = ux2 * w0.p[p] + (uy2 * w1.p[p] + (uz2 * w2.p[p] + br.p[p]));
            Btd.p[p] = __builtin_elementwise_max(td, z2);
            Btr.p[p] = __builtin_elementwise_max(tr, z2);
        }

        f32x16 acc;
        acc = __builtin_amdgcn_mfma_f32_32x32x16_f16(A1, Btd.v, accInit, 0, 0, 0);
        acc = __builtin_amdgcn_mfma_f32_32x32x16_f16(A2, Btr.v, acc,     0, 0, 0);

        // direct store: reg r -> plane h = r + 4*g, col j; t2*32 folds to imm
        #pragma unroll
        for (int r = 0; r < 4; ++r)
            pb[voff[r] + t2 * 32] = acc[r];
    }
}

extern "C" void kernel_launch(void* const* d_in, const int* in_sizes, int n_in,
                              void* d_out, int out_size, void* d_ws, size_t ws_size,
                              hipStream_t stream) {
    const float* xyz = (const float*)d_in[0];
    const float* Wd1 = (const float*)d_in[1];
    const float* bd1 = (const float*)d_in[2];
    const float* Wd2 = (const float*)d_in[3];
    const float* bd2 = (const float*)d_in[4];
    const float* Wr1 = (const float*)d_in[5];
    const float* br1 = (const float*)d_in[6];
    const float* Wr2 = (const float*)d_in[7];
    const float* br2 = (const float*)d_in[8];
    const float* Wf  = (const float*)d_in[9];
    const float* bf  = (const float*)d_in[10];
    float* out = (float*)d_out;

    erpe_main<<<BB * NN, 256, 0, stream>>>(xyz, Wd1, bd1, Wd2, bd2,
                                           Wr1, br1, Wr2, br2, Wf, bf, out);
}